// Round 1
// baseline (685.036 us; speedup 1.0000x reference)
//
#include <hip/hip_runtime.h>
#include <hip/hip_bf16.h>

#define BN_EPS 1e-5

// ---------------- CSR build ----------------

__global__ void count_kernel(const int* __restrict__ dst, int* __restrict__ cnt, int E) {
    int e = blockIdx.x * blockDim.x + threadIdx.x;
    if (e < E) atomicAdd(&cnt[dst[e]], 1);
}

__global__ void dinv_kernel(const int* __restrict__ cnt, float* __restrict__ dinv, int N) {
    int v = blockIdx.x * blockDim.x + threadIdx.x;
    if (v < N) dinv[v] = rsqrtf((float)(cnt[v] + 1));   // +1 self loop; deg>=1 always
}

// block-exclusive scan of 1024-chunks; partial into part[], block sums into bsum[]
__global__ void scan1_kernel(const int* __restrict__ cnt, int* __restrict__ part,
                             int* __restrict__ bsum, int n) {
    __shared__ int s[1024];
    int t = threadIdx.x;
    int i = blockIdx.x * 1024 + t;
    int v = (i < n) ? cnt[i] : 0;
    s[t] = v;
    __syncthreads();
    for (int off = 1; off < 1024; off <<= 1) {
        int x = (t >= off) ? s[t - off] : 0;
        __syncthreads();
        s[t] += x;
        __syncthreads();
    }
    if (i < n) part[i] = s[t] - v;       // exclusive within block
    if (t == 1023) bsum[blockIdx.x] = s[1023];
}

// exclusive scan of up to 64 block sums (single block, 64 threads)
__global__ void scan2_kernel(int* __restrict__ bsum, int nb) {
    __shared__ int s[64];
    int t = threadIdx.x;
    int v = (t < nb) ? bsum[t] : 0;
    s[t] = v;
    __syncthreads();
    for (int off = 1; off < 64; off <<= 1) {
        int x = (t >= off) ? s[t - off] : 0;
        __syncthreads();
        s[t] += x;
        __syncthreads();
    }
    if (t < nb) bsum[t] = s[t] - v;      // exclusive
}

__global__ void scan3_kernel(int* __restrict__ rowptr, const int* __restrict__ bsum,
                             int* __restrict__ cursor, int n, int E) {
    int i = blockIdx.x * blockDim.x + threadIdx.x;
    if (i < n) {
        int r = rowptr[i] + bsum[i >> 10];
        rowptr[i] = r;
        cursor[i] = r;
    }
    if (i == 0) rowptr[n] = E;
}

__global__ void fill_kernel(const int* __restrict__ src, const int* __restrict__ dst,
                            int* __restrict__ cursor, int* __restrict__ csr, int E) {
    int e = blockIdx.x * blockDim.x + threadIdx.x;
    if (e < E) {
        int d = dst[e];
        int pos = atomicAdd(&cursor[d], 1);
        csr[pos] = src[e];
    }
}

// ---------------- GCN pieces ----------------

// y[v][c] = x[v][c] * dinv[v], C=64, float4 per thread
__global__ void prescale64_kernel(const float* __restrict__ x, const float* __restrict__ dinv,
                                  float* __restrict__ y, int N) {
    int t = blockIdx.x * blockDim.x + threadIdx.x;
    int total = N * 16;                  // quads per row = 16
    if (t >= total) return;
    int r = t >> 4;
    float4 v = ((const float4*)x)[t];
    float d = dinv[r];
    v.x *= d; v.y *= d; v.z *= d; v.w *= d;
    ((float4*)y)[t] = v;
}

// one wave per node, 64 channels (1 float/lane): out[v] = dinv[v]*(y[v] + sum y[src])
__global__ void agg64_kernel(const float* __restrict__ y, const int* __restrict__ rowptr,
                             const int* __restrict__ csr, const float* __restrict__ dinv,
                             float* __restrict__ out, int N) {
    int wid = (blockIdx.x * blockDim.x + threadIdx.x) >> 6;
    int lane = threadIdx.x & 63;
    if (wid >= N) return;
    float acc = y[(size_t)wid * 64 + lane];
    int b = rowptr[wid], e = rowptr[wid + 1];
    int i = b;
    for (; i + 1 < e; i += 2) {
        int s0 = csr[i], s1 = csr[i + 1];
        acc += y[(size_t)s0 * 64 + lane];
        acc += y[(size_t)s1 * 64 + lane];
    }
    if (i < e) acc += y[(size_t)csr[i] * 64 + lane];
    out[(size_t)wid * 64 + lane] = acc * dinv[wid];
}

// one wave per node, 128 channels (float2/lane). Input already scaled by dinv[src].
__global__ void agg128_kernel(const float* __restrict__ y, const int* __restrict__ rowptr,
                              const int* __restrict__ csr, const float* __restrict__ dinv,
                              float* __restrict__ out, int N) {
    int wid = (blockIdx.x * blockDim.x + threadIdx.x) >> 6;
    int lane = threadIdx.x & 63;
    if (wid >= N) return;
    size_t c2 = (size_t)(lane << 1);
    float2 acc = *(const float2*)(y + (size_t)wid * 128 + c2);
    int b = rowptr[wid], e = rowptr[wid + 1];
    int i = b;
    for (; i + 1 < e; i += 2) {
        int s0 = csr[i], s1 = csr[i + 1];
        float2 r0 = *(const float2*)(y + (size_t)s0 * 128 + c2);
        float2 r1 = *(const float2*)(y + (size_t)s1 * 128 + c2);
        acc.x += r0.x + r1.x;
        acc.y += r0.y + r1.y;
    }
    if (i < e) {
        float2 r0 = *(const float2*)(y + (size_t)csr[i] * 128 + c2);
        acc.x += r0.x; acc.y += r0.y;
    }
    float d = dinv[wid];
    float2 o = make_float2(acc.x * d, acc.y * d);
    *(float2*)(out + (size_t)wid * 128 + c2) = o;
}

// A[N,K] @ W[K,C] + bias -> out[N,C]. Block: 256 threads = 32 rows x 128 cols tile.
// blockIdx.y = column tile of 128.
template <int K>
__global__ __launch_bounds__(256) void gemm_bias_kernel(const float* __restrict__ A,
                                                        const float* __restrict__ W,
                                                        const float* __restrict__ bias,
                                                        float* __restrict__ out, int N, int C) {
    __shared__ float Wl[K * 128];
    const int ct = blockIdx.y << 7;
    for (int idx = threadIdx.x; idx < K * 128; idx += 256) {
        int kk = idx >> 7, cc = idx & 127;
        Wl[idx] = W[(size_t)kk * C + ct + cc];
    }
    __syncthreads();
    const int cq = (threadIdx.x & 31) << 2;
    const int rg = threadIdx.x >> 5;
    const int r0 = blockIdx.x * 32 + (rg << 2);

    const float* Ap[4];
#pragma unroll
    for (int i = 0; i < 4; ++i) {
        int r = r0 + i;
        Ap[i] = A + (size_t)(r < N ? r : 0) * K;
    }
    float acc[4][4] = {};
#pragma unroll 4
    for (int k = 0; k < K; ++k) {
        float a0 = Ap[0][k];
        float a1 = Ap[1][k];
        float a2 = Ap[2][k];
        float a3 = Ap[3][k];
        float4 w = *(const float4*)&Wl[k * 128 + cq];
        acc[0][0] += a0 * w.x; acc[0][1] += a0 * w.y; acc[0][2] += a0 * w.z; acc[0][3] += a0 * w.w;
        acc[1][0] += a1 * w.x; acc[1][1] += a1 * w.y; acc[1][2] += a1 * w.z; acc[1][3] += a1 * w.w;
        acc[2][0] += a2 * w.x; acc[2][1] += a2 * w.y; acc[2][2] += a2 * w.z; acc[2][3] += a2 * w.w;
        acc[3][0] += a3 * w.x; acc[3][1] += a3 * w.y; acc[3][2] += a3 * w.z; acc[3][3] += a3 * w.w;
    }
    float4 bv = *(const float4*)&bias[ct + cq];
#pragma unroll
    for (int i = 0; i < 4; ++i) {
        int r = r0 + i;
        if (r < N) {
            float4 o = make_float4(acc[i][0] + bv.x, acc[i][1] + bv.y,
                                   acc[i][2] + bv.z, acc[i][3] + bv.w);
            *(float4*)&out[(size_t)r * C + ct + cq] = o;
        }
    }
}

// column sum / sumsq -> double accumulators st[0..C) and st[C..2C)
__global__ void colstats_kernel(const float* __restrict__ h, int N, int C, int logC,
                                double* __restrict__ st) {
    int c = threadIdx.x & (C - 1);
    int sub = threadIdx.x >> logC;
    int rpb = 256 >> logC;
    float s = 0.f, s2 = 0.f;
    for (int r = blockIdx.x * rpb + sub; r < N; r += gridDim.x * rpb) {
        float v = h[(size_t)r * C + c];
        s += v;
        s2 += v * v;
    }
    atomicAdd(&st[c], (double)s);
    atomicAdd(&st[C + c], (double)s2);
}

__global__ void bnfin_kernel(const double* __restrict__ st, const float* __restrict__ gamma,
                             const float* __restrict__ beta, float2* __restrict__ ss,
                             int N, int C) {
    int c = blockIdx.x * blockDim.x + threadIdx.x;
    if (c >= C) return;
    double mean = st[c] / N;
    double var = st[C + c] / N - mean * mean;
    float sc = (float)((double)gamma[c] / sqrt(var + BN_EPS));
    float sh = beta[c] - (float)mean * sc;
    ss[c] = make_float2(sc, sh);
}

// out = relu(h*scale+shift) [* dinv[row] if useD]
__global__ void normrelu_kernel(const float* __restrict__ h, const float2* __restrict__ ss,
                                const float* __restrict__ dinv, float* __restrict__ out,
                                int N, int C, int useD) {
    int qpr = C >> 2;
    int t = blockIdx.x * blockDim.x + threadIdx.x;
    int total = N * qpr;
    if (t >= total) return;
    int r = t / qpr;
    int j = (t - r * qpr) << 2;
    float4 v = ((const float4*)h)[t];
    float2 s0 = ss[j], s1 = ss[j + 1], s2 = ss[j + 2], s3 = ss[j + 3];
    float d = useD ? dinv[r] : 1.0f;
    v.x = fmaxf(v.x * s0.x + s0.y, 0.f) * d;
    v.y = fmaxf(v.y * s1.x + s1.y, 0.f) * d;
    v.z = fmaxf(v.z * s2.x + s2.y, 0.f) * d;
    v.w = fmaxf(v.w * s3.x + s3.y, 0.f) * d;
    ((float4*)out)[t] = v;
}

// graph boundaries from sorted batch: gstart[g] = first node index with batch >= g
__global__ void bounds_kernel(const int* __restrict__ batch, int* __restrict__ gstart,
                              int N, int G) {
    int i = blockIdx.x * blockDim.x + threadIdx.x;
    if (i >= N) return;
    int bi = batch[i];
    int bp = (i == 0) ? -1 : batch[i - 1];
    for (int g = bp + 1; g <= bi; ++g) gstart[g] = i;
    if (i == N - 1) {
        for (int g = bi + 1; g <= G; ++g) gstart[g] = N;
    }
}

// per-graph mean over rows of h [N,128] -> pooled [G,128]; one block (128 thr) per graph
__global__ void pool_kernel(const float* __restrict__ h, const int* __restrict__ gstart,
                            float* __restrict__ pooled) {
    int g = blockIdx.x;
    int c = threadIdx.x;
    int b = gstart[g], e = gstart[g + 1];
    float acc = 0.f;
    for (int r = b; r < e; ++r) acc += h[(size_t)r * 128 + c];
    pooled[(size_t)g * 128 + c] = acc / fmaxf((float)(e - b), 1.0f);
}

// final: out[g][j] = sum_c relu(bn(z))[g][c] * W4[c][j] + b4[j]
__global__ void head_kernel(const float* __restrict__ z, const float2* __restrict__ ss,
                            const float* __restrict__ W4, const float* __restrict__ b4,
                            float* __restrict__ out, int G) {
    __shared__ float zr[256];
    int g = blockIdx.x;
    int t = threadIdx.x;
    float v = z[(size_t)g * 256 + t];
    zr[t] = fmaxf(v * ss[t].x + ss[t].y, 0.f);
    __syncthreads();
    if (t < 10) {
        float acc = b4[t];
        for (int c = 0; c < 256; ++c) acc += zr[c] * W4[c * 10 + t];
        out[(size_t)g * 10 + t] = acc;
    }
}

// ---------------- launch ----------------

extern "C" void kernel_launch(void* const* d_in, const int* in_sizes, int n_in,
                              void* d_out, int out_size, void* d_ws, size_t ws_size,
                              hipStream_t stream) {
    const int N = in_sizes[0] / 64;
    const int E = in_sizes[1] / 2;
    const int G = out_size / 10;

    const float* x     = (const float*)d_in[0];
    const int*   ei    = (const int*)d_in[1];
    const int*   batch = (const int*)d_in[2];
    const float* W1 = (const float*)d_in[3];
    const float* b1 = (const float*)d_in[4];
    const float* g1 = (const float*)d_in[5];
    const float* be1 = (const float*)d_in[6];
    const float* W2 = (const float*)d_in[7];
    const float* b2 = (const float*)d_in[8];
    const float* g2 = (const float*)d_in[9];
    const float* be2 = (const float*)d_in[10];
    const float* W3 = (const float*)d_in[11];
    const float* b3 = (const float*)d_in[12];
    const float* g3 = (const float*)d_in[13];
    const float* be3 = (const float*)d_in[14];
    const float* W4 = (const float*)d_in[15];
    const float* b4 = (const float*)d_in[16];
    float* out = (float*)d_out;

    const int* srcp = ei;        // edge_index[0]
    const int* dstp = ei + E;    // edge_index[1]

    // workspace layout
    char* p = (char*)d_ws;
    auto alloc = [&](size_t bytes) {
        void* r = (void*)p;
        p += (bytes + 255) & ~(size_t)255;
        return r;
    };
    float* A  = (float*)alloc((size_t)N * 128 * 4);
    float* Bb = (float*)alloc((size_t)N * 128 * 4);
    float* Cc = (float*)alloc((size_t)N * 128 * 4);
    int* csr    = (int*)alloc((size_t)E * 4);
    int* cnt    = (int*)alloc((size_t)N * 4);
    int* rowptr = (int*)alloc((size_t)(N + 1) * 4);
    int* cursor = (int*)alloc((size_t)N * 4);
    float* dinv = (float*)alloc((size_t)N * 4);
    int* bsums  = (int*)alloc(64 * 4);
    int* gstart = (int*)alloc((size_t)(G + 1) * 4);
    float* pooled = (float*)alloc((size_t)G * 128 * 4);
    float* z      = (float*)alloc((size_t)G * 256 * 4);
    double* st    = (double*)alloc(1024 * 8);   // stA=st, stB=st+256, stC=st+512
    float2* ss    = (float2*)alloc(512 * 8);    // ssA=ss, ssB=ss+128, ssC=ss+256
    (void)ws_size; (void)n_in;

    double* stA = st;
    double* stB = st + 256;
    double* stC = st + 512;
    float2* ssA = ss;
    float2* ssB = ss + 128;
    float2* ssC = ss + 256;

    hipMemsetAsync(cnt, 0, (size_t)N * 4, stream);
    hipMemsetAsync(st, 0, 1024 * 8, stream);

    const int eb = (E + 255) / 256;
    const int nb = (N + 255) / 256;
    const int nchunks = (N + 1023) / 1024;

    count_kernel<<<eb, 256, 0, stream>>>(dstp, cnt, E);
    dinv_kernel<<<nb, 256, 0, stream>>>(cnt, dinv, N);
    scan1_kernel<<<nchunks, 1024, 0, stream>>>(cnt, rowptr, bsums, N);
    scan2_kernel<<<1, 64, 0, stream>>>(bsums, nchunks);
    scan3_kernel<<<nb, 256, 0, stream>>>(rowptr, bsums, cursor, N, E);
    fill_kernel<<<eb, 256, 0, stream>>>(srcp, dstp, cursor, csr, E);

    // Layer 1: y = x*dinv (Cc), agg -> A, gemm -> Bb
    prescale64_kernel<<<(N * 16 + 255) / 256, 256, 0, stream>>>(x, dinv, Cc, N);
    agg64_kernel<<<(N * 64 + 255) / 256, 256, 0, stream>>>(Cc, rowptr, csr, dinv, A, N);
    gemm_bias_kernel<64><<<dim3((N + 31) / 32, 1), 256, 0, stream>>>(A, W1, b1, Bb, N, 128);
    colstats_kernel<<<128, 256, 0, stream>>>(Bb, N, 128, 7, stA);
    bnfin_kernel<<<1, 128, 0, stream>>>(stA, g1, be1, ssA, N, 128);
    normrelu_kernel<<<(N * 32 + 255) / 256, 256, 0, stream>>>(Bb, ssA, dinv, Cc, N, 128, 1);

    // Layer 2: agg (Cc is hn1*dinv) -> A, gemm -> Bb, norm -> Cc (hn2)
    agg128_kernel<<<(N * 64 + 255) / 256, 256, 0, stream>>>(Cc, rowptr, csr, dinv, A, N);
    gemm_bias_kernel<128><<<dim3((N + 31) / 32, 1), 256, 0, stream>>>(A, W2, b2, Bb, N, 128);
    colstats_kernel<<<128, 256, 0, stream>>>(Bb, N, 128, 7, stB);
    bnfin_kernel<<<1, 128, 0, stream>>>(stB, g2, be2, ssB, N, 128);
    normrelu_kernel<<<(N * 32 + 255) / 256, 256, 0, stream>>>(Bb, ssB, dinv, Cc, N, 128, 0);

    // Pool
    bounds_kernel<<<nb, 256, 0, stream>>>(batch, gstart, N, G);
    pool_kernel<<<G, 128, 0, stream>>>(Cc, gstart, pooled);

    // Head: z = pooled@W3+b3 ; bn3 ; relu ; @W4+b4
    gemm_bias_kernel<128><<<dim3((G + 31) / 32, 2), 256, 0, stream>>>(pooled, W3, b3, z, G, 256);
    colstats_kernel<<<64, 256, 0, stream>>>(z, G, 256, 8, stC);
    bnfin_kernel<<<1, 256, 0, stream>>>(stC, g3, be3, ssC, G, 256);
    head_kernel<<<G, 256, 0, stream>>>(z, ssC, W4, b4, out, G);
}

// Round 2
// 556.440 us; speedup vs baseline: 1.2311x; 1.2311x over previous
//
#include <hip/hip_runtime.h>
#include <hip/hip_bf16.h>

#define BN_EPS 1e-5
#define FILL_PASSES 8

// ---------------- bf16 helpers ----------------

__device__ __forceinline__ unsigned short f2bf(float f) {
    union { float f; unsigned u; } v; v.f = f;
    unsigned r = v.u + 0x7FFF + ((v.u >> 16) & 1);   // RNE
    return (unsigned short)(r >> 16);
}
__device__ __forceinline__ float bf2f(unsigned short h) {
    union { unsigned u; float f; } v; v.u = ((unsigned)h) << 16;
    return v.f;
}

// ---------------- CSR build ----------------

__global__ void count_kernel(const int* __restrict__ dst, int* __restrict__ cnt, int E) {
    int base = (blockIdx.x * blockDim.x + threadIdx.x) * 4;
    if (base >= E) return;
    if (base + 3 < E) {
        int4 d = *(const int4*)(dst + base);
        atomicAdd(&cnt[d.x], 1);
        atomicAdd(&cnt[d.y], 1);
        atomicAdd(&cnt[d.z], 1);
        atomicAdd(&cnt[d.w], 1);
    } else {
        for (int e = base; e < E; ++e) atomicAdd(&cnt[dst[e]], 1);
    }
}

__global__ void dinv_kernel(const int* __restrict__ cnt, float* __restrict__ dinv, int N) {
    int v = blockIdx.x * blockDim.x + threadIdx.x;
    if (v < N) dinv[v] = rsqrtf((float)(cnt[v] + 1));   // +1 self loop; deg>=1 always
}

// block-exclusive scan of 1024-chunks; partial into part[], block sums into bsum[]
__global__ void scan1_kernel(const int* __restrict__ cnt, int* __restrict__ part,
                             int* __restrict__ bsum, int n) {
    __shared__ int s[1024];
    int t = threadIdx.x;
    int i = blockIdx.x * 1024 + t;
    int v = (i < n) ? cnt[i] : 0;
    s[t] = v;
    __syncthreads();
    for (int off = 1; off < 1024; off <<= 1) {
        int x = (t >= off) ? s[t - off] : 0;
        __syncthreads();
        s[t] += x;
        __syncthreads();
    }
    if (i < n) part[i] = s[t] - v;       // exclusive within block
    if (t == 1023) bsum[blockIdx.x] = s[1023];
}

// exclusive scan of up to 64 block sums (single block, 64 threads)
__global__ void scan2_kernel(int* __restrict__ bsum, int nb) {
    __shared__ int s[64];
    int t = threadIdx.x;
    int v = (t < nb) ? bsum[t] : 0;
    s[t] = v;
    __syncthreads();
    for (int off = 1; off < 64; off <<= 1) {
        int x = (t >= off) ? s[t - off] : 0;
        __syncthreads();
        s[t] += x;
        __syncthreads();
    }
    if (t < nb) bsum[t] = s[t] - v;      // exclusive
}

__global__ void scan3_kernel(int* __restrict__ rowptr, const int* __restrict__ bsum,
                             int* __restrict__ cursor, int n, int E) {
    int i = blockIdx.x * blockDim.x + threadIdx.x;
    if (i < n) {
        int r = rowptr[i] + bsum[i >> 10];
        rowptr[i] = r;
        cursor[i] = r;
    }
    if (i == 0) rowptr[n] = E;
}

// range-filtered multi-pass fill: pass p only places edges with dst in
// [p*npp, (p+1)*npp) so the csr write region (~800KB) merges in L2 before
// writeback. 1-D monotone dispatch keeps passes temporally clustered.
__global__ void fill_pass_kernel(const int* __restrict__ src, const int* __restrict__ dst,
                                 int* __restrict__ cursor, int* __restrict__ csr,
                                 int E, int bpp, int npp) {
    int pass = blockIdx.x / bpp;
    int blk  = blockIdx.x - pass * bpp;
    int lo = pass * npp;
    int hi = lo + npp;
    int base = (blk * 256 + threadIdx.x) * 4;
    if (base >= E) return;
    if (base + 3 < E) {
        int4 d4 = *(const int4*)(dst + base);
        int4 s4 = *(const int4*)(src + base);
        int dd[4] = {d4.x, d4.y, d4.z, d4.w};
        int sv[4] = {s4.x, s4.y, s4.z, s4.w};
#pragma unroll
        for (int i = 0; i < 4; ++i) {
            if (dd[i] >= lo && dd[i] < hi) {
                int pos = atomicAdd(&cursor[dd[i]], 1);
                csr[pos] = sv[i];
            }
        }
    } else {
        for (int e = base; e < E; ++e) {
            int d = dst[e];
            if (d >= lo && d < hi) {
                int pos = atomicAdd(&cursor[d], 1);
                csr[pos] = src[e];
            }
        }
    }
}

// ---------------- GCN pieces ----------------

// y16[v][c] = bf16(x[v][c] * dinv[v]), C=64; thread handles 8 channels
__global__ void prescale64_bf(const float* __restrict__ x, const float* __restrict__ dinv,
                              unsigned short* __restrict__ y, int N) {
    int t = blockIdx.x * blockDim.x + threadIdx.x;
    int total = N * 8;
    if (t >= total) return;
    int r = t >> 3;
    float d = dinv[r];
    float4 a = ((const float4*)x)[t * 2];
    float4 b = ((const float4*)x)[t * 2 + 1];
    uint4 o;
    o.x = (unsigned)f2bf(a.x * d) | ((unsigned)f2bf(a.y * d) << 16);
    o.y = (unsigned)f2bf(a.z * d) | ((unsigned)f2bf(a.w * d) << 16);
    o.z = (unsigned)f2bf(b.x * d) | ((unsigned)f2bf(b.y * d) << 16);
    o.w = (unsigned)f2bf(b.z * d) | ((unsigned)f2bf(b.w * d) << 16);
    ((uint4*)y)[t] = o;
}

// one wave per node, 64 channels (1 bf16/lane): A[v] = dinv[v]*(y[v] + sum y[src])
__global__ void agg64_bf(const unsigned short* __restrict__ y, const int* __restrict__ rowptr,
                         const int* __restrict__ csr, const float* __restrict__ dinv,
                         float* __restrict__ A, int N) {
    int wid = (blockIdx.x * blockDim.x + threadIdx.x) >> 6;
    int lane = threadIdx.x & 63;
    if (wid >= N) return;
    float acc = bf2f(y[(size_t)wid * 64 + lane]);
    int b = rowptr[wid], e = rowptr[wid + 1];
    int i = b;
    for (; i + 3 < e; i += 4) {
        int s0 = csr[i], s1 = csr[i + 1], s2 = csr[i + 2], s3 = csr[i + 3];
        float v0 = bf2f(y[(size_t)s0 * 64 + lane]);
        float v1 = bf2f(y[(size_t)s1 * 64 + lane]);
        float v2 = bf2f(y[(size_t)s2 * 64 + lane]);
        float v3 = bf2f(y[(size_t)s3 * 64 + lane]);
        acc += (v0 + v1) + (v2 + v3);
    }
    for (; i < e; ++i) acc += bf2f(y[(size_t)csr[i] * 64 + lane]);
    A[(size_t)wid * 64 + lane] = acc * dinv[wid];
}

// one wave per node, 128 channels (2 bf16 = 1 uint per lane)
__global__ void agg128_bf(const unsigned short* __restrict__ y, const int* __restrict__ rowptr,
                          const int* __restrict__ csr, const float* __restrict__ dinv,
                          float* __restrict__ A, int N) {
    int wid = (blockIdx.x * blockDim.x + threadIdx.x) >> 6;
    int lane = threadIdx.x & 63;
    if (wid >= N) return;
    const unsigned* yp = (const unsigned*)y;   // 64 uints per row
    unsigned v = yp[(size_t)wid * 64 + lane];
    float ax = bf2f((unsigned short)(v & 0xffff));
    float ay = bf2f((unsigned short)(v >> 16));
    int b = rowptr[wid], e = rowptr[wid + 1];
    int i = b;
    for (; i + 3 < e; i += 4) {
        int s0 = csr[i], s1 = csr[i + 1], s2 = csr[i + 2], s3 = csr[i + 3];
        unsigned v0 = yp[(size_t)s0 * 64 + lane];
        unsigned v1 = yp[(size_t)s1 * 64 + lane];
        unsigned v2 = yp[(size_t)s2 * 64 + lane];
        unsigned v3 = yp[(size_t)s3 * 64 + lane];
        ax += (bf2f((unsigned short)(v0 & 0xffff)) + bf2f((unsigned short)(v1 & 0xffff)))
            + (bf2f((unsigned short)(v2 & 0xffff)) + bf2f((unsigned short)(v3 & 0xffff)));
        ay += (bf2f((unsigned short)(v0 >> 16)) + bf2f((unsigned short)(v1 >> 16)))
            + (bf2f((unsigned short)(v2 >> 16)) + bf2f((unsigned short)(v3 >> 16)));
    }
    for (; i < e; ++i) {
        unsigned v0 = yp[(size_t)csr[i] * 64 + lane];
        ax += bf2f((unsigned short)(v0 & 0xffff));
        ay += bf2f((unsigned short)(v0 >> 16));
    }
    float d = dinv[wid];
    *(float2*)(A + (size_t)wid * 128 + lane * 2) = make_float2(ax * d, ay * d);
}

// A[N,K] @ W[K,C] + bias -> out[N,C]. Block: 256 threads = 32 rows x 128 cols tile.
template <int K>
__global__ __launch_bounds__(256) void gemm_bias_kernel(const float* __restrict__ A,
                                                        const float* __restrict__ W,
                                                        const float* __restrict__ bias,
                                                        float* __restrict__ out, int N, int C) {
    __shared__ float Wl[K * 128];
    const int ct = blockIdx.y << 7;
    for (int idx = threadIdx.x; idx < K * 128; idx += 256) {
        int kk = idx >> 7, cc = idx & 127;
        Wl[idx] = W[(size_t)kk * C + ct + cc];
    }
    __syncthreads();
    const int cq = (threadIdx.x & 31) << 2;
    const int rg = threadIdx.x >> 5;
    const int r0 = blockIdx.x * 32 + (rg << 2);

    const float* Ap[4];
#pragma unroll
    for (int i = 0; i < 4; ++i) {
        int r = r0 + i;
        Ap[i] = A + (size_t)(r < N ? r : 0) * K;
    }
    float acc[4][4] = {};
#pragma unroll 4
    for (int k = 0; k < K; ++k) {
        float a0 = Ap[0][k];
        float a1 = Ap[1][k];
        float a2 = Ap[2][k];
        float a3 = Ap[3][k];
        float4 w = *(const float4*)&Wl[k * 128 + cq];
        acc[0][0] += a0 * w.x; acc[0][1] += a0 * w.y; acc[0][2] += a0 * w.z; acc[0][3] += a0 * w.w;
        acc[1][0] += a1 * w.x; acc[1][1] += a1 * w.y; acc[1][2] += a1 * w.z; acc[1][3] += a1 * w.w;
        acc[2][0] += a2 * w.x; acc[2][1] += a2 * w.y; acc[2][2] += a2 * w.z; acc[2][3] += a2 * w.w;
        acc[3][0] += a3 * w.x; acc[3][1] += a3 * w.y; acc[3][2] += a3 * w.z; acc[3][3] += a3 * w.w;
    }
    float4 bv = *(const float4*)&bias[ct + cq];
#pragma unroll
    for (int i = 0; i < 4; ++i) {
        int r = r0 + i;
        if (r < N) {
            float4 o = make_float4(acc[i][0] + bv.x, acc[i][1] + bv.y,
                                   acc[i][2] + bv.z, acc[i][3] + bv.w);
            *(float4*)&out[(size_t)r * C + ct + cq] = o;
        }
    }
}

// column sum / sumsq -> double accumulators st[0..C) and st[C..2C)
__global__ void colstats_kernel(const float* __restrict__ h, int N, int C, int logC,
                                double* __restrict__ st) {
    int c = threadIdx.x & (C - 1);
    int sub = threadIdx.x >> logC;
    int rpb = 256 >> logC;
    float s = 0.f, s2 = 0.f;
    for (int r = blockIdx.x * rpb + sub; r < N; r += gridDim.x * rpb) {
        float v = h[(size_t)r * C + c];
        s += v;
        s2 += v * v;
    }
    atomicAdd(&st[c], (double)s);
    atomicAdd(&st[C + c], (double)s2);
}

__global__ void bnfin_kernel(const double* __restrict__ st, const float* __restrict__ gamma,
                             const float* __restrict__ beta, float2* __restrict__ ss,
                             int N, int C) {
    int c = blockIdx.x * blockDim.x + threadIdx.x;
    if (c >= C) return;
    double mean = st[c] / N;
    double var = st[C + c] / N - mean * mean;
    float sc = (float)((double)gamma[c] / sqrt(var + BN_EPS));
    float sh = beta[c] - (float)mean * sc;
    ss[c] = make_float2(sc, sh);
}

// out16 = bf16(relu(h*scale+shift) * dinv[row]), C=128; thread handles 8 ch
__global__ void normrelu_bf(const float* __restrict__ h, const float2* __restrict__ ss,
                            const float* __restrict__ dinv, unsigned short* __restrict__ out,
                            int N) {
    int t = blockIdx.x * blockDim.x + threadIdx.x;
    int total = N * 16;
    if (t >= total) return;
    int r = t >> 4;
    int j = (t & 15) << 3;
    float d = dinv[r];
    float4 a = ((const float4*)h)[t * 2];
    float4 b = ((const float4*)h)[t * 2 + 1];
    float2 s0 = ss[j], s1 = ss[j + 1], s2 = ss[j + 2], s3 = ss[j + 3];
    float2 s4 = ss[j + 4], s5 = ss[j + 5], s6 = ss[j + 6], s7 = ss[j + 7];
    float v0 = fmaxf(a.x * s0.x + s0.y, 0.f) * d;
    float v1 = fmaxf(a.y * s1.x + s1.y, 0.f) * d;
    float v2 = fmaxf(a.z * s2.x + s2.y, 0.f) * d;
    float v3 = fmaxf(a.w * s3.x + s3.y, 0.f) * d;
    float v4 = fmaxf(b.x * s4.x + s4.y, 0.f) * d;
    float v5 = fmaxf(b.y * s5.x + s5.y, 0.f) * d;
    float v6 = fmaxf(b.z * s6.x + s6.y, 0.f) * d;
    float v7 = fmaxf(b.w * s7.x + s7.y, 0.f) * d;
    uint4 o;
    o.x = (unsigned)f2bf(v0) | ((unsigned)f2bf(v1) << 16);
    o.y = (unsigned)f2bf(v2) | ((unsigned)f2bf(v3) << 16);
    o.z = (unsigned)f2bf(v4) | ((unsigned)f2bf(v5) << 16);
    o.w = (unsigned)f2bf(v6) | ((unsigned)f2bf(v7) << 16);
    ((uint4*)out)[t] = o;
}

// out = relu(h*scale+shift), f32 (layer 2 output for pooling)
__global__ void normrelu_kernel(const float* __restrict__ h, const float2* __restrict__ ss,
                                float* __restrict__ out, int N, int C) {
    int qpr = C >> 2;
    int t = blockIdx.x * blockDim.x + threadIdx.x;
    int total = N * qpr;
    if (t >= total) return;
    int r = t / qpr;
    int j = (t - r * qpr) << 2;
    float4 v = ((const float4*)h)[t];
    float2 s0 = ss[j], s1 = ss[j + 1], s2 = ss[j + 2], s3 = ss[j + 3];
    v.x = fmaxf(v.x * s0.x + s0.y, 0.f);
    v.y = fmaxf(v.y * s1.x + s1.y, 0.f);
    v.z = fmaxf(v.z * s2.x + s2.y, 0.f);
    v.w = fmaxf(v.w * s3.x + s3.y, 0.f);
    ((float4*)out)[t] = v;
}

// graph boundaries from sorted batch
__global__ void bounds_kernel(const int* __restrict__ batch, int* __restrict__ gstart,
                              int N, int G) {
    int i = blockIdx.x * blockDim.x + threadIdx.x;
    if (i >= N) return;
    int bi = batch[i];
    int bp = (i == 0) ? -1 : batch[i - 1];
    for (int g = bp + 1; g <= bi; ++g) gstart[g] = i;
    if (i == N - 1) {
        for (int g = bi + 1; g <= G; ++g) gstart[g] = N;
    }
}

// per-graph mean over rows of h [N,128] -> pooled [G,128]
__global__ void pool_kernel(const float* __restrict__ h, const int* __restrict__ gstart,
                            float* __restrict__ pooled) {
    int g = blockIdx.x;
    int c = threadIdx.x;
    int b = gstart[g], e = gstart[g + 1];
    float acc = 0.f;
    for (int r = b; r < e; ++r) acc += h[(size_t)r * 128 + c];
    pooled[(size_t)g * 128 + c] = acc / fmaxf((float)(e - b), 1.0f);
}

// final: out[g][j] = sum_c relu(bn(z))[g][c] * W4[c][j] + b4[j]
__global__ void head_kernel(const float* __restrict__ z, const float2* __restrict__ ss,
                            const float* __restrict__ W4, const float* __restrict__ b4,
                            float* __restrict__ out, int G) {
    __shared__ float zr[256];
    int g = blockIdx.x;
    int t = threadIdx.x;
    float v = z[(size_t)g * 256 + t];
    zr[t] = fmaxf(v * ss[t].x + ss[t].y, 0.f);
    __syncthreads();
    if (t < 10) {
        float acc = b4[t];
        for (int c = 0; c < 256; ++c) acc += zr[c] * W4[c * 10 + t];
        out[(size_t)g * 10 + t] = acc;
    }
}

// ---------------- launch ----------------

extern "C" void kernel_launch(void* const* d_in, const int* in_sizes, int n_in,
                              void* d_out, int out_size, void* d_ws, size_t ws_size,
                              hipStream_t stream) {
    const int N = in_sizes[0] / 64;
    const int E = in_sizes[1] / 2;
    const int G = out_size / 10;

    const float* x     = (const float*)d_in[0];
    const int*   ei    = (const int*)d_in[1];
    const int*   batch = (const int*)d_in[2];
    const float* W1 = (const float*)d_in[3];
    const float* b1 = (const float*)d_in[4];
    const float* g1 = (const float*)d_in[5];
    const float* be1 = (const float*)d_in[6];
    const float* W2 = (const float*)d_in[7];
    const float* b2 = (const float*)d_in[8];
    const float* g2 = (const float*)d_in[9];
    const float* be2 = (const float*)d_in[10];
    const float* W3 = (const float*)d_in[11];
    const float* b3 = (const float*)d_in[12];
    const float* g3 = (const float*)d_in[13];
    const float* be3 = (const float*)d_in[14];
    const float* W4 = (const float*)d_in[15];
    const float* b4 = (const float*)d_in[16];
    float* out = (float*)d_out;

    const int* srcp = ei;        // edge_index[0]
    const int* dstp = ei + E;    // edge_index[1]

    // workspace layout
    char* p = (char*)d_ws;
    auto alloc = [&](size_t bytes) {
        void* r = (void*)p;
        p += (bytes + 255) & ~(size_t)255;
        return r;
    };
    float* A  = (float*)alloc((size_t)N * 128 * 4);
    float* Bb = (float*)alloc((size_t)N * 128 * 4);
    float* Cc = (float*)alloc((size_t)N * 128 * 4);   // also hosts the bf16 buffers
    int* csr    = (int*)alloc((size_t)E * 4);
    int* cnt    = (int*)alloc((size_t)N * 4);
    int* rowptr = (int*)alloc((size_t)(N + 1) * 4);
    int* cursor = (int*)alloc((size_t)N * 4);
    float* dinv = (float*)alloc((size_t)N * 4);
    int* bsums  = (int*)alloc(64 * 4);
    int* gstart = (int*)alloc((size_t)(G + 1) * 4);
    float* pooled = (float*)alloc((size_t)G * 128 * 4);
    float* z      = (float*)alloc((size_t)G * 256 * 4);
    double* st    = (double*)alloc(1024 * 8);
    float2* ss    = (float2*)alloc(512 * 8);
    (void)ws_size; (void)n_in;

    // bf16 staging buffers alias Cc's storage (disjoint lifetimes):
    //   c16 [N*128 bf16] = first 12.8MB of Cc;  y16 [N*64 bf16] = next 6.4MB.
    // Cc as f32 is only written by normrelu_kernel AFTER agg128_bf consumed c16.
    unsigned short* c16 = (unsigned short*)Cc;
    unsigned short* y16 = (unsigned short*)(Cc + (size_t)N * 64);

    double* stA = st;
    double* stB = st + 256;
    double* stC = st + 512;
    float2* ssA = ss;
    float2* ssB = ss + 128;
    float2* ssC = ss + 256;

    hipMemsetAsync(cnt, 0, (size_t)N * 4, stream);
    hipMemsetAsync(st, 0, 1024 * 8, stream);

    const int nb = (N + 255) / 256;
    const int nchunks = (N + 1023) / 1024;

    count_kernel<<<(E / 4 + 255) / 256, 256, 0, stream>>>(dstp, cnt, E);
    dinv_kernel<<<nb, 256, 0, stream>>>(cnt, dinv, N);
    scan1_kernel<<<nchunks, 1024, 0, stream>>>(cnt, rowptr, bsums, N);
    scan2_kernel<<<1, 64, 0, stream>>>(bsums, nchunks);
    scan3_kernel<<<nb, 256, 0, stream>>>(rowptr, bsums, cursor, N, E);

    const int bpp = (E + 1023) / 1024;                   // blocks per pass (4 edges/thread)
    const int npp = (N + FILL_PASSES - 1) / FILL_PASSES; // nodes per pass
    fill_pass_kernel<<<bpp * FILL_PASSES, 256, 0, stream>>>(srcp, dstp, cursor, csr, E, bpp, npp);

    // Layer 1
    prescale64_bf<<<(N * 8 + 255) / 256, 256, 0, stream>>>(x, dinv, y16, N);
    agg64_bf<<<(N * 64 + 255) / 256, 256, 0, stream>>>(y16, rowptr, csr, dinv, A, N);
    gemm_bias_kernel<64><<<dim3((N + 31) / 32, 1), 256, 0, stream>>>(A, W1, b1, Bb, N, 128);
    colstats_kernel<<<128, 256, 0, stream>>>(Bb, N, 128, 7, stA);
    bnfin_kernel<<<1, 128, 0, stream>>>(stA, g1, be1, ssA, N, 128);
    normrelu_bf<<<(N * 16 + 255) / 256, 256, 0, stream>>>(Bb, ssA, dinv, c16, N);

    // Layer 2
    agg128_bf<<<(N * 64 + 255) / 256, 256, 0, stream>>>(c16, rowptr, csr, dinv, A, N);
    gemm_bias_kernel<128><<<dim3((N + 31) / 32, 1), 256, 0, stream>>>(A, W2, b2, Bb, N, 128);
    colstats_kernel<<<128, 256, 0, stream>>>(Bb, N, 128, 7, stB);
    bnfin_kernel<<<1, 128, 0, stream>>>(stB, g2, be2, ssB, N, 128);
    normrelu_kernel<<<(N * 32 + 255) / 256, 256, 0, stream>>>(Bb, ssB, Cc, N, 128);

    // Pool
    bounds_kernel<<<nb, 256, 0, stream>>>(batch, gstart, N, G);
    pool_kernel<<<G, 128, 0, stream>>>(Cc, gstart, pooled);

    // Head
    gemm_bias_kernel<128><<<dim3((G + 31) / 32, 2), 256, 0, stream>>>(pooled, W3, b3, z, G, 256);
    colstats_kernel<<<64, 256, 0, stream>>>(z, G, 256, 8, stC);
    bnfin_kernel<<<1, 256, 0, stream>>>(stC, g3, be3, ssC, G, 256);
    head_kernel<<<G, 256, 0, stream>>>(z, ssC, W4, b4, out, G);
}

// Round 3
// 466.065 us; speedup vs baseline: 1.4698x; 1.1939x over previous
//
#include <hip/hip_runtime.h>
#include <hip/hip_bf16.h>

#define BN_EPS 1e-5
#define PB 256   // partition blocks for edge binning

typedef __attribute__((ext_vector_type(8))) short short8;
typedef __attribute__((ext_vector_type(4))) float floatx4;

// ---------------- bf16 helpers ----------------

__device__ __forceinline__ unsigned short f2bf(float f) {
    union { float f; unsigned u; } v; v.f = f;
    unsigned r = v.u + 0x7FFF + ((v.u >> 16) & 1);   // RNE
    return (unsigned short)(r >> 16);
}
__device__ __forceinline__ float bf2f(unsigned short h) {
    union { unsigned u; float f; } v; v.u = ((unsigned)h) << 16;
    return v.f;
}

// ---------------- degree / rowptr ----------------

__global__ void count_kernel(const int* __restrict__ dst, int* __restrict__ cnt, int E) {
    int base = (blockIdx.x * blockDim.x + threadIdx.x) * 4;
    if (base >= E) return;
    if (base + 3 < E) {
        int4 d = *(const int4*)(dst + base);
        atomicAdd(&cnt[d.x], 1);
        atomicAdd(&cnt[d.y], 1);
        atomicAdd(&cnt[d.z], 1);
        atomicAdd(&cnt[d.w], 1);
    } else {
        for (int e = base; e < E; ++e) atomicAdd(&cnt[dst[e]], 1);
    }
}

__global__ void dinv_kernel(const int* __restrict__ cnt, float* __restrict__ dinv, int N) {
    int v = blockIdx.x * blockDim.x + threadIdx.x;
    if (v < N) dinv[v] = rsqrtf((float)(cnt[v] + 1));   // +1 self loop
}

// block-exclusive scan of 1024-chunks
__global__ void scan1_kernel(const int* __restrict__ in, int* __restrict__ part,
                             int* __restrict__ bsum, int n) {
    __shared__ int s[1024];
    int t = threadIdx.x;
    int i = blockIdx.x * 1024 + t;
    int v = (i < n) ? in[i] : 0;
    s[t] = v;
    __syncthreads();
    for (int off = 1; off < 1024; off <<= 1) {
        int x = (t >= off) ? s[t - off] : 0;
        __syncthreads();
        s[t] += x;
        __syncthreads();
    }
    if (i < n) part[i] = s[t] - v;
    if (t == 1023) bsum[blockIdx.x] = s[1023];
}

__global__ void scan2_kernel(int* __restrict__ bsum, int nb) {
    __shared__ int s[64];
    int t = threadIdx.x;
    int v = (t < nb) ? bsum[t] : 0;
    s[t] = v;
    __syncthreads();
    for (int off = 1; off < 64; off <<= 1) {
        int x = (t >= off) ? s[t - off] : 0;
        __syncthreads();
        s[t] += x;
        __syncthreads();
    }
    if (t < nb) bsum[t] = s[t] - v;
}

__global__ void scan3_rowptr(int* __restrict__ rowptr, const int* __restrict__ bsum,
                             int n, int E) {
    int i = blockIdx.x * blockDim.x + threadIdx.x;
    if (i < n) rowptr[i] += bsum[i >> 10];
    if (i == 0) rowptr[n] = E;
}

__global__ void scan3_add(int* __restrict__ arr, const int* __restrict__ bsum, int n) {
    int i = blockIdx.x * blockDim.x + threadIdx.x;
    if (i < n) arr[i] += bsum[i >> 10];
}

// ---------------- ownership-based CSR fill ----------------
// bucket(d) = d >> 8 ; NB buckets, PB partition blocks.

// per-(block,bucket) histogram, bucket-major layout hist[b*PB + blk]
__global__ void hist_kernel(const int* __restrict__ dst, int* __restrict__ hist,
                            int E, int cpb, int NB) {
    __shared__ int h[256];
    int t = threadIdx.x;
    if (t < NB) h[t] = 0;
    __syncthreads();
    int base = blockIdx.x * cpb;
    int end = base + cpb; if (end > E) end = E;
    for (int e = base + t; e < end; e += 256) atomicAdd(&h[dst[e] >> 8], 1);
    __syncthreads();
    if (t < NB) hist[t * PB + blockIdx.x] = h[t];
}

// scatter edges into bucket-sorted (src,dst) pairs; per-(block,bucket) runs contiguous
__global__ void scatter_kernel(const int* __restrict__ src, const int* __restrict__ dst,
                               const int* __restrict__ offs, int2* __restrict__ part,
                               int E, int cpb, int NB) {
    __shared__ int cur[256];
    int t = threadIdx.x;
    if (t < NB) cur[t] = offs[t * PB + blockIdx.x];
    __syncthreads();
    int base = blockIdx.x * cpb;
    int end = base + cpb; if (end > E) end = E;
    for (int e = base + t; e < end; e += 256) {
        int d = dst[e];
        int pos = atomicAdd(&cur[d >> 8], 1);
        part[pos] = make_int2(src[e], d);
    }
}

// one block per bucket: fill csr slice with LDS node cursors (single-XCD writes)
__global__ void bucket_fill(const int2* __restrict__ part, const int* __restrict__ offs,
                            const int* __restrict__ rowptr, int* __restrict__ csr,
                            int E, int N, int NB) {
    __shared__ int cur[256];
    int b = blockIdx.x;
    int t = threadIdx.x;
    int lo = b << 8;
    int node = lo + t;
    cur[t] = (node < N) ? rowptr[node] : 0;
    __syncthreads();
    int bstart = offs[b * PB];
    int bend = (b + 1 < NB) ? offs[(b + 1) * PB] : E;
    for (int e = bstart + t; e < bend; e += 256) {
        int2 pr = part[e];
        int pos = atomicAdd(&cur[pr.y - lo], 1);
        csr[pos] = pr.x;
    }
}

// ---------------- GCN pieces ----------------

// y16[v][c] = bf16(x[v][c] * dinv[v]), C=64
__global__ void prescale64_bf(const float* __restrict__ x, const float* __restrict__ dinv,
                              unsigned short* __restrict__ y, int N) {
    int t = blockIdx.x * blockDim.x + threadIdx.x;
    int total = N * 8;
    if (t >= total) return;
    int r = t >> 3;
    float d = dinv[r];
    float4 a = ((const float4*)x)[t * 2];
    float4 b = ((const float4*)x)[t * 2 + 1];
    uint4 o;
    o.x = (unsigned)f2bf(a.x * d) | ((unsigned)f2bf(a.y * d) << 16);
    o.y = (unsigned)f2bf(a.z * d) | ((unsigned)f2bf(a.w * d) << 16);
    o.z = (unsigned)f2bf(b.x * d) | ((unsigned)f2bf(b.y * d) << 16);
    o.w = (unsigned)f2bf(b.z * d) | ((unsigned)f2bf(b.w * d) << 16);
    ((uint4*)y)[t] = o;
}

// one wave per node, 64 ch: A16[v] = bf16(dinv[v]*(y[v] + sum y[src]))
__global__ void agg64_bf(const unsigned short* __restrict__ y, const int* __restrict__ rowptr,
                         const int* __restrict__ csr, const float* __restrict__ dinv,
                         unsigned short* __restrict__ A16, int N) {
    int wid = (blockIdx.x * blockDim.x + threadIdx.x) >> 6;
    int lane = threadIdx.x & 63;
    if (wid >= N) return;
    float acc = bf2f(y[(size_t)wid * 64 + lane]);
    int b = rowptr[wid], e = rowptr[wid + 1];
    int i = b;
    for (; i + 3 < e; i += 4) {
        int s0 = csr[i], s1 = csr[i + 1], s2 = csr[i + 2], s3 = csr[i + 3];
        float v0 = bf2f(y[(size_t)s0 * 64 + lane]);
        float v1 = bf2f(y[(size_t)s1 * 64 + lane]);
        float v2 = bf2f(y[(size_t)s2 * 64 + lane]);
        float v3 = bf2f(y[(size_t)s3 * 64 + lane]);
        acc += (v0 + v1) + (v2 + v3);
    }
    for (; i < e; ++i) acc += bf2f(y[(size_t)csr[i] * 64 + lane]);
    A16[(size_t)wid * 64 + lane] = f2bf(acc * dinv[wid]);
}

// one wave per node, 128 ch (2 bf16 = 1 uint per lane)
__global__ void agg128_bf(const unsigned short* __restrict__ y, const int* __restrict__ rowptr,
                          const int* __restrict__ csr, const float* __restrict__ dinv,
                          unsigned short* __restrict__ A16, int N) {
    int wid = (blockIdx.x * blockDim.x + threadIdx.x) >> 6;
    int lane = threadIdx.x & 63;
    if (wid >= N) return;
    const unsigned* yp = (const unsigned*)y;
    unsigned v = yp[(size_t)wid * 64 + lane];
    float ax = bf2f((unsigned short)(v & 0xffff));
    float ay = bf2f((unsigned short)(v >> 16));
    int b = rowptr[wid], e = rowptr[wid + 1];
    int i = b;
    for (; i + 3 < e; i += 4) {
        int s0 = csr[i], s1 = csr[i + 1], s2 = csr[i + 2], s3 = csr[i + 3];
        unsigned v0 = yp[(size_t)s0 * 64 + lane];
        unsigned v1 = yp[(size_t)s1 * 64 + lane];
        unsigned v2 = yp[(size_t)s2 * 64 + lane];
        unsigned v3 = yp[(size_t)s3 * 64 + lane];
        ax += (bf2f((unsigned short)(v0 & 0xffff)) + bf2f((unsigned short)(v1 & 0xffff)))
            + (bf2f((unsigned short)(v2 & 0xffff)) + bf2f((unsigned short)(v3 & 0xffff)));
        ay += (bf2f((unsigned short)(v0 >> 16)) + bf2f((unsigned short)(v1 >> 16)))
            + (bf2f((unsigned short)(v2 >> 16)) + bf2f((unsigned short)(v3 >> 16)));
    }
    for (; i < e; ++i) {
        unsigned v0 = yp[(size_t)csr[i] * 64 + lane];
        ax += bf2f((unsigned short)(v0 & 0xffff));
        ay += bf2f((unsigned short)(v0 >> 16));
    }
    float d = dinv[wid];
    ((unsigned*)A16)[(size_t)wid * 64 + lane] =
        (unsigned)f2bf(ax * d) | ((unsigned)f2bf(ay * d) << 16);
}

// pack W[K][128] fp32 -> Wp[kb][c] = uint4 of 8 bf16 (k = kb*8+j)
__global__ void wpack_kernel(const float* __restrict__ W, uint4* __restrict__ Wp, int K) {
    int i = blockIdx.x * blockDim.x + threadIdx.x;
    int total = K * 16;            // (K/8)*128
    if (i >= total) return;
    int c = i & 127;
    int kb = i >> 7;
    unsigned short h[8];
#pragma unroll
    for (int j = 0; j < 8; ++j) h[j] = f2bf(W[(size_t)(kb * 8 + j) * 128 + c]);
    uint4 o;
    o.x = (unsigned)h[0] | ((unsigned)h[1] << 16);
    o.y = (unsigned)h[2] | ((unsigned)h[3] << 16);
    o.z = (unsigned)h[4] | ((unsigned)h[5] << 16);
    o.w = (unsigned)h[6] | ((unsigned)h[7] << 16);
    Wp[kb * 128 + c] = o;
}

// MFMA GEMM: A16[N][K] bf16 @ Wp (packed K x 128 bf16) -> out[N][128] fp32 (no bias;
// BN absorbs per-column constants). Block = 4 waves = 64 rows; wave = 16 rows x 128 cols.
template <int K>
__global__ __launch_bounds__(256) void mfma_gemm(const unsigned short* __restrict__ A16,
                                                 const uint4* __restrict__ Bp,
                                                 float* __restrict__ out, int N) {
    constexpr int KS = K / 32;
    int w = threadIdx.x >> 6, l = threadIdx.x & 63;
    int cl = l & 15, sub = l >> 4;
    int r0 = blockIdx.x * 64 + w * 16;
    int ra = r0 + cl; if (ra > N - 1) ra = N - 1;

    short8 a[KS];
    const unsigned short* ap = A16 + (size_t)ra * K + sub * 8;
#pragma unroll
    for (int ks = 0; ks < KS; ++ks) a[ks] = *(const short8*)(ap + ks * 32);

    floatx4 acc[8] = {};
#pragma unroll
    for (int cb = 0; cb < 8; ++cb) {
#pragma unroll
        for (int ks = 0; ks < KS; ++ks) {
            short8 b = *(const short8*)&Bp[(ks * 4 + sub) * 128 + cb * 16 + cl];
            acc[cb] = __builtin_amdgcn_mfma_f32_16x16x32_bf16(a[ks], b, acc[cb], 0, 0, 0);
        }
    }
#pragma unroll
    for (int cb = 0; cb < 8; ++cb) {
#pragma unroll
        for (int j = 0; j < 4; ++j) {
            int row = r0 + sub * 4 + j;
            if (row < N) out[(size_t)row * 128 + cb * 16 + cl] = acc[cb][j];
        }
    }
}

// column sum / sumsq -> double accumulators st[0..C) and st[C..2C)
__global__ void colstats_kernel(const float* __restrict__ h, int N, int C, int logC,
                                double* __restrict__ st) {
    int c = threadIdx.x & (C - 1);
    int sub = threadIdx.x >> logC;
    int rpb = 256 >> logC;
    float s = 0.f, s2 = 0.f;
    for (int r = blockIdx.x * rpb + sub; r < N; r += gridDim.x * rpb) {
        float v = h[(size_t)r * C + c];
        s += v;
        s2 += v * v;
    }
    atomicAdd(&st[c], (double)s);
    atomicAdd(&st[C + c], (double)s2);
}

__global__ void bnfin_kernel(const double* __restrict__ st, const float* __restrict__ gamma,
                             const float* __restrict__ beta, float2* __restrict__ ss,
                             int N, int C) {
    int c = blockIdx.x * blockDim.x + threadIdx.x;
    if (c >= C) return;
    double mean = st[c] / N;
    double var = st[C + c] / N - mean * mean;
    float sc = (float)((double)gamma[c] / sqrt(var + BN_EPS));
    float sh = beta[c] - (float)mean * sc;
    ss[c] = make_float2(sc, sh);
}

// out16 = bf16(relu(h*scale+shift) * dinv[row]), C=128
__global__ void normrelu_bf(const float* __restrict__ h, const float2* __restrict__ ss,
                            const float* __restrict__ dinv, unsigned short* __restrict__ out,
                            int N) {
    int t = blockIdx.x * blockDim.x + threadIdx.x;
    int total = N * 16;
    if (t >= total) return;
    int r = t >> 4;
    int j = (t & 15) << 3;
    float d = dinv[r];
    float4 a = ((const float4*)h)[t * 2];
    float4 b = ((const float4*)h)[t * 2 + 1];
    float2 s0 = ss[j], s1 = ss[j + 1], s2 = ss[j + 2], s3 = ss[j + 3];
    float2 s4 = ss[j + 4], s5 = ss[j + 5], s6 = ss[j + 6], s7 = ss[j + 7];
    float v0 = fmaxf(a.x * s0.x + s0.y, 0.f) * d;
    float v1 = fmaxf(a.y * s1.x + s1.y, 0.f) * d;
    float v2 = fmaxf(a.z * s2.x + s2.y, 0.f) * d;
    float v3 = fmaxf(a.w * s3.x + s3.y, 0.f) * d;
    float v4 = fmaxf(b.x * s4.x + s4.y, 0.f) * d;
    float v5 = fmaxf(b.y * s5.x + s5.y, 0.f) * d;
    float v6 = fmaxf(b.z * s6.x + s6.y, 0.f) * d;
    float v7 = fmaxf(b.w * s7.x + s7.y, 0.f) * d;
    uint4 o;
    o.x = (unsigned)f2bf(v0) | ((unsigned)f2bf(v1) << 16);
    o.y = (unsigned)f2bf(v2) | ((unsigned)f2bf(v3) << 16);
    o.z = (unsigned)f2bf(v4) | ((unsigned)f2bf(v5) << 16);
    o.w = (unsigned)f2bf(v6) | ((unsigned)f2bf(v7) << 16);
    ((uint4*)out)[t] = o;
}

// out = relu(h*scale+shift), f32 (layer 2 output for pooling)
__global__ void normrelu_kernel(const float* __restrict__ h, const float2* __restrict__ ss,
                                float* __restrict__ out, int N, int C) {
    int qpr = C >> 2;
    int t = blockIdx.x * blockDim.x + threadIdx.x;
    int total = N * qpr;
    if (t >= total) return;
    int r = t / qpr;
    int j = (t - r * qpr) << 2;
    float4 v = ((const float4*)h)[t];
    float2 s0 = ss[j], s1 = ss[j + 1], s2 = ss[j + 2], s3 = ss[j + 3];
    v.x = fmaxf(v.x * s0.x + s0.y, 0.f);
    v.y = fmaxf(v.y * s1.x + s1.y, 0.f);
    v.z = fmaxf(v.z * s2.x + s2.y, 0.f);
    v.w = fmaxf(v.w * s3.x + s3.y, 0.f);
    ((float4*)out)[t] = v;
}

// graph boundaries from sorted batch
__global__ void bounds_kernel(const int* __restrict__ batch, int* __restrict__ gstart,
                              int N, int G) {
    int i = blockIdx.x * blockDim.x + threadIdx.x;
    if (i >= N) return;
    int bi = batch[i];
    int bp = (i == 0) ? -1 : batch[i - 1];
    for (int g = bp + 1; g <= bi; ++g) gstart[g] = i;
    if (i == N - 1) {
        for (int g = bi + 1; g <= G; ++g) gstart[g] = N;
    }
}

// per-graph mean over rows of h [N,128] -> pooled [G,128]
__global__ void pool_kernel(const float* __restrict__ h, const int* __restrict__ gstart,
                            float* __restrict__ pooled) {
    int g = blockIdx.x;
    int c = threadIdx.x;
    int b = gstart[g], e = gstart[g + 1];
    float acc = 0.f;
    for (int r = b; r < e; ++r) acc += h[(size_t)r * 128 + c];
    pooled[(size_t)g * 128 + c] = acc / fmaxf((float)(e - b), 1.0f);
}

// head gemm (fp32, small): A[N,K] @ W[K,C] + bias -> out[N,C]
template <int K>
__global__ __launch_bounds__(256) void gemm_bias_kernel(const float* __restrict__ A,
                                                        const float* __restrict__ W,
                                                        const float* __restrict__ bias,
                                                        float* __restrict__ out, int N, int C) {
    __shared__ float Wl[K * 128];
    const int ct = blockIdx.y << 7;
    for (int idx = threadIdx.x; idx < K * 128; idx += 256) {
        int kk = idx >> 7, cc = idx & 127;
        Wl[idx] = W[(size_t)kk * C + ct + cc];
    }
    __syncthreads();
    const int cq = (threadIdx.x & 31) << 2;
    const int rg = threadIdx.x >> 5;
    const int r0 = blockIdx.x * 32 + (rg << 2);

    const float* Ap[4];
#pragma unroll
    for (int i = 0; i < 4; ++i) {
        int r = r0 + i;
        Ap[i] = A + (size_t)(r < N ? r : 0) * K;
    }
    float acc[4][4] = {};
#pragma unroll 4
    for (int k = 0; k < K; ++k) {
        float a0 = Ap[0][k];
        float a1 = Ap[1][k];
        float a2 = Ap[2][k];
        float a3 = Ap[3][k];
        float4 w = *(const float4*)&Wl[k * 128 + cq];
        acc[0][0] += a0 * w.x; acc[0][1] += a0 * w.y; acc[0][2] += a0 * w.z; acc[0][3] += a0 * w.w;
        acc[1][0] += a1 * w.x; acc[1][1] += a1 * w.y; acc[1][2] += a1 * w.z; acc[1][3] += a1 * w.w;
        acc[2][0] += a2 * w.x; acc[2][1] += a2 * w.y; acc[2][2] += a2 * w.z; acc[2][3] += a2 * w.w;
        acc[3][0] += a3 * w.x; acc[3][1] += a3 * w.y; acc[3][2] += a3 * w.z; acc[3][3] += a3 * w.w;
    }
    float4 bv = *(const float4*)&bias[ct + cq];
#pragma unroll
    for (int i = 0; i < 4; ++i) {
        int r = r0 + i;
        if (r < N) {
            float4 o = make_float4(acc[i][0] + bv.x, acc[i][1] + bv.y,
                                   acc[i][2] + bv.z, acc[i][3] + bv.w);
            *(float4*)&out[(size_t)r * C + ct + cq] = o;
        }
    }
}

// final: out[g][j] = sum_c relu(bn(z))[g][c] * W4[c][j] + b4[j]
__global__ void head_kernel(const float* __restrict__ z, const float2* __restrict__ ss,
                            const float* __restrict__ W4, const float* __restrict__ b4,
                            float* __restrict__ out, int G) {
    __shared__ float zr[256];
    int g = blockIdx.x;
    int t = threadIdx.x;
    float v = z[(size_t)g * 256 + t];
    zr[t] = fmaxf(v * ss[t].x + ss[t].y, 0.f);
    __syncthreads();
    if (t < 10) {
        float acc = b4[t];
        for (int c = 0; c < 256; ++c) acc += zr[c] * W4[c * 10 + t];
        out[(size_t)g * 10 + t] = acc;
    }
}

// ---------------- launch ----------------

extern "C" void kernel_launch(void* const* d_in, const int* in_sizes, int n_in,
                              void* d_out, int out_size, void* d_ws, size_t ws_size,
                              hipStream_t stream) {
    const int N = in_sizes[0] / 64;
    const int E = in_sizes[1] / 2;
    const int G = out_size / 10;

    const float* x     = (const float*)d_in[0];
    const int*   ei    = (const int*)d_in[1];
    const int*   batch = (const int*)d_in[2];
    const float* W1 = (const float*)d_in[3];
    const float* g1 = (const float*)d_in[5];
    const float* be1 = (const float*)d_in[6];
    const float* W2 = (const float*)d_in[7];
    const float* g2 = (const float*)d_in[9];
    const float* be2 = (const float*)d_in[10];
    const float* W3 = (const float*)d_in[11];
    const float* b3 = (const float*)d_in[12];
    const float* g3 = (const float*)d_in[13];
    const float* be3 = (const float*)d_in[14];
    const float* W4 = (const float*)d_in[15];
    const float* b4 = (const float*)d_in[16];
    float* out = (float*)d_out;

    const int* srcp = ei;        // edge_index[0]
    const int* dstp = ei + E;    // edge_index[1]

    // workspace layout
    char* p = (char*)d_ws;
    auto alloc = [&](size_t bytes) {
        void* r = (void*)p;
        p += (bytes + 255) & ~(size_t)255;
        return r;
    };
    // A16 region hosts A16_1 [N][64] then A16_2 [N][128] (disjoint lifetimes)
    unsigned short* A16 = (unsigned short*)alloc((size_t)N * 128 * 2);
    float* Bb = (float*)alloc((size_t)N * 128 * 4);
    char* R3  = (char*)alloc((size_t)N * 128 * 4);   // c16 | y16 | later Cc f32
    int* csr    = (int*)alloc((size_t)E * 4);
    int2* part  = (int2*)alloc((size_t)E * 8);
    int* cnt    = (int*)alloc((size_t)N * 4);
    int* rowptr = (int*)alloc((size_t)(N + 1) * 4);
    float* dinv = (float*)alloc((size_t)N * 4);
    int* hist   = (int*)alloc((size_t)256 * PB * 4);
    int* offs   = (int*)alloc((size_t)256 * PB * 4);
    int* bsums  = (int*)alloc(64 * 4);
    uint4* w1p  = (uint4*)alloc((size_t)64 * 128 * 2);    // 64*16 uint4
    uint4* w2p  = (uint4*)alloc((size_t)128 * 128 * 2);   // 128*16 uint4
    int* gstart = (int*)alloc((size_t)(G + 1) * 4);
    float* pooled = (float*)alloc((size_t)G * 128 * 4);
    float* z      = (float*)alloc((size_t)G * 256 * 4);
    double* st    = (double*)alloc(1024 * 8);
    float2* ss    = (float2*)alloc(512 * 8);
    (void)ws_size; (void)n_in;

    unsigned short* c16 = (unsigned short*)R3;                       // [N*128] bf16
    unsigned short* y16 = (unsigned short*)(R3 + (size_t)N * 128 * 2); // [N*64] bf16
    float* Cc = (float*)R3;                                          // [N*128] f32 (later)

    double* stA = st;
    double* stB = st + 256;
    double* stC = st + 512;
    float2* ssA = ss;
    float2* ssB = ss + 128;
    float2* ssC = ss + 256;

    hipMemsetAsync(cnt, 0, (size_t)N * 4, stream);
    hipMemsetAsync(st, 0, 1024 * 8, stream);

    const int nb = (N + 255) / 256;
    const int nchunks = (N + 1023) / 1024;
    const int NB = (N + 255) >> 8;                  // buckets (196 for N=50000)
    const int cpb = (E + PB - 1) / PB;              // edges per partition block
    const int n2 = NB * PB;
    const int nch2 = (n2 + 1023) / 1024;

    // weight packing (independent)
    wpack_kernel<<<4, 256, 0, stream>>>(W1, w1p, 64);
    wpack_kernel<<<8, 256, 0, stream>>>(W2, w2p, 128);

    // degree + rowptr
    count_kernel<<<(E / 4 + 255) / 256, 256, 0, stream>>>(dstp, cnt, E);
    dinv_kernel<<<nb, 256, 0, stream>>>(cnt, dinv, N);
    scan1_kernel<<<nchunks, 1024, 0, stream>>>(cnt, rowptr, bsums, N);
    scan2_kernel<<<1, 64, 0, stream>>>(bsums, nchunks);
    scan3_rowptr<<<nb, 256, 0, stream>>>(rowptr, bsums, N, E);

    // ownership-based CSR fill
    hist_kernel<<<PB, 256, 0, stream>>>(dstp, hist, E, cpb, NB);
    scan1_kernel<<<nch2, 1024, 0, stream>>>(hist, offs, bsums, n2);
    scan2_kernel<<<1, 64, 0, stream>>>(bsums, nch2);
    scan3_add<<<(n2 + 255) / 256, 256, 0, stream>>>(offs, bsums, n2);
    scatter_kernel<<<PB, 256, 0, stream>>>(srcp, dstp, offs, part, E, cpb, NB);
    bucket_fill<<<NB, 256, 0, stream>>>(part, offs, rowptr, csr, E, N, NB);

    // Layer 1
    prescale64_bf<<<(N * 8 + 255) / 256, 256, 0, stream>>>(x, dinv, y16, N);
    agg64_bf<<<(N * 64 + 255) / 256, 256, 0, stream>>>(y16, rowptr, csr, dinv, A16, N);
    mfma_gemm<64><<<(N + 63) / 64, 256, 0, stream>>>(A16, w1p, Bb, N);
    colstats_kernel<<<128, 256, 0, stream>>>(Bb, N, 128, 7, stA);
    bnfin_kernel<<<1, 128, 0, stream>>>(stA, g1, be1, ssA, N, 128);
    normrelu_bf<<<(N * 16 + 255) / 256, 256, 0, stream>>>(Bb, ssA, dinv, c16, N);

    // Layer 2
    agg128_bf<<<(N * 64 + 255) / 256, 256, 0, stream>>>(c16, rowptr, csr, dinv, A16, N);
    mfma_gemm<128><<<(N + 63) / 64, 256, 0, stream>>>(A16, w2p, Bb, N);
    colstats_kernel<<<128, 256, 0, stream>>>(Bb, N, 128, 7, stB);
    bnfin_kernel<<<1, 128, 0, stream>>>(stB, g2, be2, ssB, N, 128);
    normrelu_kernel<<<(N * 32 + 255) / 256, 256, 0, stream>>>(Bb, ssB, Cc, N, 128);

    // Pool
    bounds_kernel<<<nb, 256, 0, stream>>>(batch, gstart, N, G);
    pool_kernel<<<G, 128, 0, stream>>>(Cc, gstart, pooled);

    // Head
    gemm_bias_kernel<128><<<dim3((G + 31) / 32, 2), 256, 0, stream>>>(pooled, W3, b3, z, G, 256);
    colstats_kernel<<<64, 256, 0, stream>>>(z, G, 256, 8, stC);
    bnfin_kernel<<<1, 256, 0, stream>>>(stC, g3, be3, ssC, G, 256);
    head_kernel<<<G, 256, 0, stream>>>(z, ssC, W4, b4, out, G);
}

// Round 4
// 388.918 us; speedup vs baseline: 1.7614x; 1.1984x over previous
//
#include <hip/hip_runtime.h>
#include <hip/hip_bf16.h>

#define BN_EPS 1e-5
#define PB 256   // partition blocks for edge binning

typedef __attribute__((ext_vector_type(8))) short short8;
typedef __attribute__((ext_vector_type(4))) float floatx4;

// ---------------- bf16 helpers ----------------

__device__ __forceinline__ unsigned short f2bf(float f) {
    union { float f; unsigned u; } v; v.f = f;
    unsigned r = v.u + 0x7FFF + ((v.u >> 16) & 1);   // RNE
    return (unsigned short)(r >> 16);
}
__device__ __forceinline__ float bf2f(unsigned short h) {
    union { unsigned u; float f; } v; v.u = ((unsigned)h) << 16;
    return v.f;
}

// ---------------- scans ----------------

__global__ void scan1_kernel(const int* __restrict__ in, int* __restrict__ part,
                             int* __restrict__ bsum, int n) {
    __shared__ int s[1024];
    int t = threadIdx.x;
    int i = blockIdx.x * 1024 + t;
    int v = (i < n) ? in[i] : 0;
    s[t] = v;
    __syncthreads();
    for (int off = 1; off < 1024; off <<= 1) {
        int x = (t >= off) ? s[t - off] : 0;
        __syncthreads();
        s[t] += x;
        __syncthreads();
    }
    if (i < n) part[i] = s[t] - v;
    if (t == 1023) bsum[blockIdx.x] = s[1023];
}

__global__ void scan2_kernel(int* __restrict__ bsum, int nb) {
    __shared__ int s[64];
    int t = threadIdx.x;
    int v = (t < nb) ? bsum[t] : 0;
    s[t] = v;
    __syncthreads();
    for (int off = 1; off < 64; off <<= 1) {
        int x = (t >= off) ? s[t - off] : 0;
        __syncthreads();
        s[t] += x;
        __syncthreads();
    }
    if (t < nb) bsum[t] = s[t] - v;
}

__global__ void scan3_rowptr(int* __restrict__ rowptr, const int* __restrict__ bsum,
                             int n, int E) {
    int i = blockIdx.x * blockDim.x + threadIdx.x;
    if (i < n) rowptr[i] += bsum[i >> 10];
    if (i == 0) rowptr[n] = E;
}

__global__ void scan3_add(int* __restrict__ arr, const int* __restrict__ bsum, int n) {
    int i = blockIdx.x * blockDim.x + threadIdx.x;
    if (i < n) arr[i] += bsum[i >> 10];
}

// ---------------- ownership-based CSR build ----------------
// bucket(d) = d >> 8 ; NB buckets, PB partition blocks. No global atomics anywhere.

// per-(block,bucket) histogram, bucket-major layout hist[b*PB + blk]
__global__ void hist_kernel(const int* __restrict__ dst, int* __restrict__ hist,
                            int E, int cpb, int NB) {
    __shared__ int h[256];
    int t = threadIdx.x;
    if (t < NB) h[t] = 0;
    __syncthreads();
    int base = blockIdx.x * cpb;
    int end = base + cpb; if (end > E) end = E;
    int e = base + t * 4;
    for (; e + 3 < end; e += 1024) {
        int4 d = *(const int4*)(dst + e);
        atomicAdd(&h[d.x >> 8], 1);
        atomicAdd(&h[d.y >> 8], 1);
        atomicAdd(&h[d.z >> 8], 1);
        atomicAdd(&h[d.w >> 8], 1);
    }
    for (; e < end; ++e) atomicAdd(&h[dst[e] >> 8], 1);
    __syncthreads();
    if (t < NB) hist[t * PB + blockIdx.x] = h[t];
}

// scatter edges into bucket-sorted packed entries (src<<8 | dst&255)
__global__ void scatter_kernel(const int* __restrict__ src, const int* __restrict__ dst,
                               const int* __restrict__ offs, unsigned* __restrict__ part,
                               int E, int cpb, int NB) {
    __shared__ int cur[256];
    int t = threadIdx.x;
    if (t < NB) cur[t] = offs[t * PB + blockIdx.x];
    __syncthreads();
    int base = blockIdx.x * cpb;
    int end = base + cpb; if (end > E) end = E;
    int e = base + t * 4;
    for (; e + 3 < end; e += 1024) {
        int4 d4 = *(const int4*)(dst + e);
        int4 s4 = *(const int4*)(src + e);
        int dd[4] = {d4.x, d4.y, d4.z, d4.w};
        int sv[4] = {s4.x, s4.y, s4.z, s4.w};
#pragma unroll
        for (int i = 0; i < 4; ++i) {
            int pos = atomicAdd(&cur[dd[i] >> 8], 1);
            part[pos] = ((unsigned)sv[i] << 8) | (unsigned)(dd[i] & 255);
        }
    }
    for (; e < end; ++e) {
        int d = dst[e];
        int pos = atomicAdd(&cur[d >> 8], 1);
        part[pos] = ((unsigned)src[e] << 8) | (unsigned)(d & 255);
    }
}

// one block per bucket: per-node degree via LDS counts; contiguous cnt/dinv writes
__global__ void bucket_count(const unsigned* __restrict__ part, const int* __restrict__ offs,
                             int* __restrict__ cnt, float* __restrict__ dinv,
                             int E, int N, int NB) {
    __shared__ int cw[256];
    int b = blockIdx.x;
    int t = threadIdx.x;
    cw[t] = 0;
    __syncthreads();
    int bstart = offs[b * PB];
    int bend = (b + 1 < NB) ? offs[(b + 1) * PB] : E;
    for (int e = bstart + t; e < bend; e += 256)
        atomicAdd(&cw[part[e] & 255u], 1);
    __syncthreads();
    int node = (b << 8) + t;
    if (node < N) {
        int c = cw[t];
        cnt[node] = c;
        dinv[node] = rsqrtf((float)(c + 1));   // +1 self loop
    }
}

// one block per bucket: fill csr slice with LDS node cursors (single-XCD writes)
__global__ void bucket_fill(const unsigned* __restrict__ part, const int* __restrict__ offs,
                            const int* __restrict__ rowptr, int* __restrict__ csr,
                            int E, int N, int NB) {
    __shared__ int cur[256];
    int b = blockIdx.x;
    int t = threadIdx.x;
    int node = (b << 8) + t;
    cur[t] = (node < N) ? rowptr[node] : 0;
    __syncthreads();
    int bstart = offs[b * PB];
    int bend = (b + 1 < NB) ? offs[(b + 1) * PB] : E;
    for (int e = bstart + t; e < bend; e += 256) {
        unsigned pr = part[e];
        int pos = atomicAdd(&cur[pr & 255u], 1);
        csr[pos] = (int)(pr >> 8);
    }
}

// ---------------- GCN pieces ----------------

// y16[v][c] = bf16(x[v][c] * dinv[v]), C=64
__global__ void prescale64_bf(const float* __restrict__ x, const float* __restrict__ dinv,
                              unsigned short* __restrict__ y, int N) {
    int t = blockIdx.x * blockDim.x + threadIdx.x;
    int total = N * 8;
    if (t >= total) return;
    int r = t >> 3;
    float d = dinv[r];
    float4 a = ((const float4*)x)[t * 2];
    float4 b = ((const float4*)x)[t * 2 + 1];
    uint4 o;
    o.x = (unsigned)f2bf(a.x * d) | ((unsigned)f2bf(a.y * d) << 16);
    o.y = (unsigned)f2bf(a.z * d) | ((unsigned)f2bf(a.w * d) << 16);
    o.z = (unsigned)f2bf(b.x * d) | ((unsigned)f2bf(b.y * d) << 16);
    o.w = (unsigned)f2bf(b.z * d) | ((unsigned)f2bf(b.w * d) << 16);
    ((uint4*)y)[t] = o;
}

// one wave per node, 64 ch: A16[v] = bf16(dinv[v]*(y[v] + sum y[src]))
__global__ void agg64_bf(const unsigned short* __restrict__ y, const int* __restrict__ rowptr,
                         const int* __restrict__ csr, const float* __restrict__ dinv,
                         unsigned short* __restrict__ A16, int N) {
    int wid = (blockIdx.x * blockDim.x + threadIdx.x) >> 6;
    int lane = threadIdx.x & 63;
    if (wid >= N) return;
    float acc = bf2f(y[(size_t)wid * 64 + lane]);
    int b = rowptr[wid], e = rowptr[wid + 1];
    int i = b;
    for (; i + 3 < e; i += 4) {
        int s0 = csr[i], s1 = csr[i + 1], s2 = csr[i + 2], s3 = csr[i + 3];
        float v0 = bf2f(y[(size_t)s0 * 64 + lane]);
        float v1 = bf2f(y[(size_t)s1 * 64 + lane]);
        float v2 = bf2f(y[(size_t)s2 * 64 + lane]);
        float v3 = bf2f(y[(size_t)s3 * 64 + lane]);
        acc += (v0 + v1) + (v2 + v3);
    }
    for (; i < e; ++i) acc += bf2f(y[(size_t)csr[i] * 64 + lane]);
    A16[(size_t)wid * 64 + lane] = f2bf(acc * dinv[wid]);
}

// one wave per node, 128 ch (2 bf16 = 1 uint per lane)
__global__ void agg128_bf(const unsigned short* __restrict__ y, const int* __restrict__ rowptr,
                          const int* __restrict__ csr, const float* __restrict__ dinv,
                          unsigned short* __restrict__ A16, int N) {
    int wid = (blockIdx.x * blockDim.x + threadIdx.x) >> 6;
    int lane = threadIdx.x & 63;
    if (wid >= N) return;
    const unsigned* yp = (const unsigned*)y;
    unsigned v = yp[(size_t)wid * 64 + lane];
    float ax = bf2f((unsigned short)(v & 0xffff));
    float ay = bf2f((unsigned short)(v >> 16));
    int b = rowptr[wid], e = rowptr[wid + 1];
    int i = b;
    for (; i + 3 < e; i += 4) {
        int s0 = csr[i], s1 = csr[i + 1], s2 = csr[i + 2], s3 = csr[i + 3];
        unsigned v0 = yp[(size_t)s0 * 64 + lane];
        unsigned v1 = yp[(size_t)s1 * 64 + lane];
        unsigned v2 = yp[(size_t)s2 * 64 + lane];
        unsigned v3 = yp[(size_t)s3 * 64 + lane];
        ax += (bf2f((unsigned short)(v0 & 0xffff)) + bf2f((unsigned short)(v1 & 0xffff)))
            + (bf2f((unsigned short)(v2 & 0xffff)) + bf2f((unsigned short)(v3 & 0xffff)));
        ay += (bf2f((unsigned short)(v0 >> 16)) + bf2f((unsigned short)(v1 >> 16)))
            + (bf2f((unsigned short)(v2 >> 16)) + bf2f((unsigned short)(v3 >> 16)));
    }
    for (; i < e; ++i) {
        unsigned v0 = yp[(size_t)csr[i] * 64 + lane];
        ax += bf2f((unsigned short)(v0 & 0xffff));
        ay += bf2f((unsigned short)(v0 >> 16));
    }
    float d = dinv[wid];
    ((unsigned*)A16)[(size_t)wid * 64 + lane] =
        (unsigned)f2bf(ax * d) | ((unsigned)f2bf(ay * d) << 16);
}

// pack W[K][128] fp32 -> Wp[kb][c] = uint4 of 8 bf16 (k = kb*8+j)
__global__ void wpack_kernel(const float* __restrict__ W, uint4* __restrict__ Wp, int K) {
    int i = blockIdx.x * blockDim.x + threadIdx.x;
    int total = K * 16;            // (K/8)*128
    if (i >= total) return;
    int c = i & 127;
    int kb = i >> 7;
    unsigned short h[8];
#pragma unroll
    for (int j = 0; j < 8; ++j) h[j] = f2bf(W[(size_t)(kb * 8 + j) * 128 + c]);
    uint4 o;
    o.x = (unsigned)h[0] | ((unsigned)h[1] << 16);
    o.y = (unsigned)h[2] | ((unsigned)h[3] << 16);
    o.z = (unsigned)h[4] | ((unsigned)h[5] << 16);
    o.w = (unsigned)h[6] | ((unsigned)h[7] << 16);
    Wp[kb * 128 + c] = o;
}

// MFMA GEMM: A16[N][K] bf16 @ Wp (packed K x 128 bf16) -> out[N][128] fp32 (no bias;
// BN absorbs per-column constants). Block = 4 waves = 64 rows; wave = 16 rows x 128 cols.
template <int K>
__global__ __launch_bounds__(256) void mfma_gemm(const unsigned short* __restrict__ A16,
                                                 const uint4* __restrict__ Bp,
                                                 float* __restrict__ out, int N) {
    constexpr int KS = K / 32;
    int w = threadIdx.x >> 6, l = threadIdx.x & 63;
    int cl = l & 15, sub = l >> 4;
    int r0 = blockIdx.x * 64 + w * 16;
    int ra = r0 + cl; if (ra > N - 1) ra = N - 1;

    short8 a[KS];
    const unsigned short* ap = A16 + (size_t)ra * K + sub * 8;
#pragma unroll
    for (int ks = 0; ks < KS; ++ks) a[ks] = *(const short8*)(ap + ks * 32);

    floatx4 acc[8] = {};
#pragma unroll
    for (int cb = 0; cb < 8; ++cb) {
#pragma unroll
        for (int ks = 0; ks < KS; ++ks) {
            short8 b = *(const short8*)&Bp[(ks * 4 + sub) * 128 + cb * 16 + cl];
            acc[cb] = __builtin_amdgcn_mfma_f32_16x16x32_bf16(a[ks], b, acc[cb], 0, 0, 0);
        }
    }
#pragma unroll
    for (int cb = 0; cb < 8; ++cb) {
#pragma unroll
        for (int j = 0; j < 4; ++j) {
            int row = r0 + sub * 4 + j;
            if (row < N) out[(size_t)row * 128 + cb * 16 + cl] = acc[cb][j];
        }
    }
}

// column sum / sumsq -> double accumulators st[0..C) and st[C..2C)
__global__ void colstats_kernel(const float* __restrict__ h, int N, int C, int logC,
                                double* __restrict__ st) {
    int c = threadIdx.x & (C - 1);
    int sub = threadIdx.x >> logC;
    int rpb = 256 >> logC;
    float s = 0.f, s2 = 0.f;
    for (int r = blockIdx.x * rpb + sub; r < N; r += gridDim.x * rpb) {
        float v = h[(size_t)r * C + c];
        s += v;
        s2 += v * v;
    }
    atomicAdd(&st[c], (double)s);
    atomicAdd(&st[C + c], (double)s2);
}

__global__ void bnfin_kernel(const double* __restrict__ st, const float* __restrict__ gamma,
                             const float* __restrict__ beta, float2* __restrict__ ss,
                             int N, int C) {
    int c = blockIdx.x * blockDim.x + threadIdx.x;
    if (c >= C) return;
    double mean = st[c] / N;
    double var = st[C + c] / N - mean * mean;
    float sc = (float)((double)gamma[c] / sqrt(var + BN_EPS));
    float sh = beta[c] - (float)mean * sc;
    ss[c] = make_float2(sc, sh);
}

// out16 = bf16(relu(h*scale+shift) * dinv[row]), C=128
__global__ void normrelu_bf(const float* __restrict__ h, const float2* __restrict__ ss,
                            const float* __restrict__ dinv, unsigned short* __restrict__ out,
                            int N) {
    int t = blockIdx.x * blockDim.x + threadIdx.x;
    int total = N * 16;
    if (t >= total) return;
    int r = t >> 4;
    int j = (t & 15) << 3;
    float d = dinv[r];
    float4 a = ((const float4*)h)[t * 2];
    float4 b = ((const float4*)h)[t * 2 + 1];
    float2 s0 = ss[j], s1 = ss[j + 1], s2 = ss[j + 2], s3 = ss[j + 3];
    float2 s4 = ss[j + 4], s5 = ss[j + 5], s6 = ss[j + 6], s7 = ss[j + 7];
    float v0 = fmaxf(a.x * s0.x + s0.y, 0.f) * d;
    float v1 = fmaxf(a.y * s1.x + s1.y, 0.f) * d;
    float v2 = fmaxf(a.z * s2.x + s2.y, 0.f) * d;
    float v3 = fmaxf(a.w * s3.x + s3.y, 0.f) * d;
    float v4 = fmaxf(b.x * s4.x + s4.y, 0.f) * d;
    float v5 = fmaxf(b.y * s5.x + s5.y, 0.f) * d;
    float v6 = fmaxf(b.z * s6.x + s6.y, 0.f) * d;
    float v7 = fmaxf(b.w * s7.x + s7.y, 0.f) * d;
    uint4 o;
    o.x = (unsigned)f2bf(v0) | ((unsigned)f2bf(v1) << 16);
    o.y = (unsigned)f2bf(v2) | ((unsigned)f2bf(v3) << 16);
    o.z = (unsigned)f2bf(v4) | ((unsigned)f2bf(v5) << 16);
    o.w = (unsigned)f2bf(v6) | ((unsigned)f2bf(v7) << 16);
    ((uint4*)out)[t] = o;
}

// out = relu(h*scale+shift), f32 (layer 2 output for pooling)
__global__ void normrelu_kernel(const float* __restrict__ h, const float2* __restrict__ ss,
                                float* __restrict__ out, int N, int C) {
    int qpr = C >> 2;
    int t = blockIdx.x * blockDim.x + threadIdx.x;
    int total = N * qpr;
    if (t >= total) return;
    int r = t / qpr;
    int j = (t - r * qpr) << 2;
    float4 v = ((const float4*)h)[t];
    float2 s0 = ss[j], s1 = ss[j + 1], s2 = ss[j + 2], s3 = ss[j + 3];
    v.x = fmaxf(v.x * s0.x + s0.y, 0.f);
    v.y = fmaxf(v.y * s1.x + s1.y, 0.f);
    v.z = fmaxf(v.z * s2.x + s2.y, 0.f);
    v.w = fmaxf(v.w * s3.x + s3.y, 0.f);
    ((float4*)out)[t] = v;
}

// graph boundaries from sorted batch
__global__ void bounds_kernel(const int* __restrict__ batch, int* __restrict__ gstart,
                              int N, int G) {
    int i = blockIdx.x * blockDim.x + threadIdx.x;
    if (i >= N) return;
    int bi = batch[i];
    int bp = (i == 0) ? -1 : batch[i - 1];
    for (int g = bp + 1; g <= bi; ++g) gstart[g] = i;
    if (i == N - 1) {
        for (int g = bi + 1; g <= G; ++g) gstart[g] = N;
    }
}

// per-graph mean over rows of h [N,128] -> pooled [G,128]
__global__ void pool_kernel(const float* __restrict__ h, const int* __restrict__ gstart,
                            float* __restrict__ pooled) {
    int g = blockIdx.x;
    int c = threadIdx.x;
    int b = gstart[g], e = gstart[g + 1];
    float acc = 0.f;
    for (int r = b; r < e; ++r) acc += h[(size_t)r * 128 + c];
    pooled[(size_t)g * 128 + c] = acc / fmaxf((float)(e - b), 1.0f);
}

// head gemm (fp32, small): A[N,K] @ W[K,C] + bias -> out[N,C]
template <int K>
__global__ __launch_bounds__(256) void gemm_bias_kernel(const float* __restrict__ A,
                                                        const float* __restrict__ W,
                                                        const float* __restrict__ bias,
                                                        float* __restrict__ out, int N, int C) {
    __shared__ float Wl[K * 128];
    const int ct = blockIdx.y << 7;
    for (int idx = threadIdx.x; idx < K * 128; idx += 256) {
        int kk = idx >> 7, cc = idx & 127;
        Wl[idx] = W[(size_t)kk * C + ct + cc];
    }
    __syncthreads();
    const int cq = (threadIdx.x & 31) << 2;
    const int rg = threadIdx.x >> 5;
    const int r0 = blockIdx.x * 32 + (rg << 2);

    const float* Ap[4];
#pragma unroll
    for (int i = 0; i < 4; ++i) {
        int r = r0 + i;
        Ap[i] = A + (size_t)(r < N ? r : 0) * K;
    }
    float acc[4][4] = {};
#pragma unroll 4
    for (int k = 0; k < K; ++k) {
        float a0 = Ap[0][k];
        float a1 = Ap[1][k];
        float a2 = Ap[2][k];
        float a3 = Ap[3][k];
        float4 w = *(const float4*)&Wl[k * 128 + cq];
        acc[0][0] += a0 * w.x; acc[0][1] += a0 * w.y; acc[0][2] += a0 * w.z; acc[0][3] += a0 * w.w;
        acc[1][0] += a1 * w.x; acc[1][1] += a1 * w.y; acc[1][2] += a1 * w.z; acc[1][3] += a1 * w.w;
        acc[2][0] += a2 * w.x; acc[2][1] += a2 * w.y; acc[2][2] += a2 * w.z; acc[2][3] += a2 * w.w;
        acc[3][0] += a3 * w.x; acc[3][1] += a3 * w.y; acc[3][2] += a3 * w.z; acc[3][3] += a3 * w.w;
    }
    float4 bv = *(const float4*)&bias[ct + cq];
#pragma unroll
    for (int i = 0; i < 4; ++i) {
        int r = r0 + i;
        if (r < N) {
            float4 o = make_float4(acc[i][0] + bv.x, acc[i][1] + bv.y,
                                   acc[i][2] + bv.z, acc[i][3] + bv.w);
            *(float4*)&out[(size_t)r * C + ct + cq] = o;
        }
    }
}

// final: out[g][j] = sum_c relu(bn(z))[g][c] * W4[c][j] + b4[j]
__global__ void head_kernel(const float* __restrict__ z, const float2* __restrict__ ss,
                            const float* __restrict__ W4, const float* __restrict__ b4,
                            float* __restrict__ out, int G) {
    __shared__ float zr[256];
    int g = blockIdx.x;
    int t = threadIdx.x;
    float v = z[(size_t)g * 256 + t];
    zr[t] = fmaxf(v * ss[t].x + ss[t].y, 0.f);
    __syncthreads();
    if (t < 10) {
        float acc = b4[t];
        for (int c = 0; c < 256; ++c) acc += zr[c] * W4[c * 10 + t];
        out[(size_t)g * 10 + t] = acc;
    }
}

// ---------------- launch ----------------

extern "C" void kernel_launch(void* const* d_in, const int* in_sizes, int n_in,
                              void* d_out, int out_size, void* d_ws, size_t ws_size,
                              hipStream_t stream) {
    const int N = in_sizes[0] / 64;
    const int E = in_sizes[1] / 2;
    const int G = out_size / 10;

    const float* x     = (const float*)d_in[0];
    const int*   ei    = (const int*)d_in[1];
    const int*   batch = (const int*)d_in[2];
    const float* W1 = (const float*)d_in[3];
    const float* g1 = (const float*)d_in[5];
    const float* be1 = (const float*)d_in[6];
    const float* W2 = (const float*)d_in[7];
    const float* g2 = (const float*)d_in[9];
    const float* be2 = (const float*)d_in[10];
    const float* W3 = (const float*)d_in[11];
    const float* b3 = (const float*)d_in[12];
    const float* g3 = (const float*)d_in[13];
    const float* be3 = (const float*)d_in[14];
    const float* W4 = (const float*)d_in[15];
    const float* b4 = (const float*)d_in[16];
    float* out = (float*)d_out;

    const int* srcp = ei;        // edge_index[0]
    const int* dstp = ei + E;    // edge_index[1]

    // workspace layout
    char* p = (char*)d_ws;
    auto alloc = [&](size_t bytes) {
        void* r = (void*)p;
        p += (bytes + 255) & ~(size_t)255;
        return r;
    };
    unsigned short* A16 = (unsigned short*)alloc((size_t)N * 128 * 2);
    float* Bb = (float*)alloc((size_t)N * 128 * 4);
    char* R3  = (char*)alloc((size_t)N * 128 * 4);   // c16 | y16 | later Cc f32
    int* csr      = (int*)alloc((size_t)E * 4);
    unsigned* part = (unsigned*)alloc((size_t)E * 4);
    int* cnt    = (int*)alloc((size_t)N * 4);
    int* rowptr = (int*)alloc((size_t)(N + 1) * 4);
    float* dinv = (float*)alloc((size_t)N * 4);
    int* hist   = (int*)alloc((size_t)256 * PB * 4);
    int* offs   = (int*)alloc((size_t)256 * PB * 4);
    int* bsums  = (int*)alloc(64 * 4);
    uint4* w1p  = (uint4*)alloc((size_t)64 * 128 * 2);
    uint4* w2p  = (uint4*)alloc((size_t)128 * 128 * 2);
    int* gstart = (int*)alloc((size_t)(G + 1) * 4);
    float* pooled = (float*)alloc((size_t)G * 128 * 4);
    float* z      = (float*)alloc((size_t)G * 256 * 4);
    double* st    = (double*)alloc(1024 * 8);
    float2* ss    = (float2*)alloc(512 * 8);
    (void)ws_size; (void)n_in;

    unsigned short* c16 = (unsigned short*)R3;                         // [N*128] bf16
    unsigned short* y16 = (unsigned short*)(R3 + (size_t)N * 128 * 2); // [N*64] bf16
    float* Cc = (float*)R3;                                            // [N*128] f32 (later)

    double* stA = st;
    double* stB = st + 256;
    double* stC = st + 512;
    float2* ssA = ss;
    float2* ssB = ss + 128;
    float2* ssC = ss + 256;

    hipMemsetAsync(st, 0, 1024 * 8, stream);

    const int nb = (N + 255) / 256;
    const int nchunks = (N + 1023) / 1024;
    const int NB = (N + 255) >> 8;                       // buckets (196 for N=50000)
    const int cpb = (((E + PB - 1) / PB) + 3) & ~3;      // edges per partition block (x4 aligned)
    const int n2 = NB * PB;
    const int nch2 = (n2 + 1023) / 1024;

    // weight packing (independent)
    wpack_kernel<<<4, 256, 0, stream>>>(W1, w1p, 64);
    wpack_kernel<<<8, 256, 0, stream>>>(W2, w2p, 128);

    // partition edges by dst bucket (no global atomics)
    hist_kernel<<<PB, 256, 0, stream>>>(dstp, hist, E, cpb, NB);
    scan1_kernel<<<nch2, 1024, 0, stream>>>(hist, offs, bsums, n2);
    scan2_kernel<<<1, 64, 0, stream>>>(bsums, nch2);
    scan3_add<<<(n2 + 255) / 256, 256, 0, stream>>>(offs, bsums, n2);
    scatter_kernel<<<PB, 256, 0, stream>>>(srcp, dstp, offs, part, E, cpb, NB);

    // degrees + dinv from partition (LDS counts, contiguous writes)
    bucket_count<<<NB, 256, 0, stream>>>(part, offs, cnt, dinv, E, N, NB);

    // rowptr = exscan(cnt), then CSR fill
    scan1_kernel<<<nchunks, 1024, 0, stream>>>(cnt, rowptr, bsums, N);
    scan2_kernel<<<1, 64, 0, stream>>>(bsums, nchunks);
    scan3_rowptr<<<nb, 256, 0, stream>>>(rowptr, bsums, N, E);
    bucket_fill<<<NB, 256, 0, stream>>>(part, offs, rowptr, csr, E, N, NB);

    // Layer 1
    prescale64_bf<<<(N * 8 + 255) / 256, 256, 0, stream>>>(x, dinv, y16, N);
    agg64_bf<<<(N * 64 + 255) / 256, 256, 0, stream>>>(y16, rowptr, csr, dinv, A16, N);
    mfma_gemm<64><<<(N + 63) / 64, 256, 0, stream>>>(A16, w1p, Bb, N);
    colstats_kernel<<<128, 256, 0, stream>>>(Bb, N, 128, 7, stA);
    bnfin_kernel<<<1, 128, 0, stream>>>(stA, g1, be1, ssA, N, 128);
    normrelu_bf<<<(N * 16 + 255) / 256, 256, 0, stream>>>(Bb, ssA, dinv, c16, N);

    // Layer 2
    agg128_bf<<<(N * 64 + 255) / 256, 256, 0, stream>>>(c16, rowptr, csr, dinv, A16, N);
    mfma_gemm<128><<<(N + 63) / 64, 256, 0, stream>>>(A16, w2p, Bb, N);
    colstats_kernel<<<128, 256, 0, stream>>>(Bb, N, 128, 7, stB);
    bnfin_kernel<<<1, 128, 0, stream>>>(stB, g2, be2, ssB, N, 128);
    normrelu_kernel<<<(N * 32 + 255) / 256, 256, 0, stream>>>(Bb, ssB, Cc, N, 128);

    // Pool
    bounds_kernel<<<nb, 256, 0, stream>>>(batch, gstart, N, G);
    pool_kernel<<<G, 128, 0, stream>>>(Cc, gstart, pooled);

    // Head
    gemm_bias_kernel<128><<<dim3((G + 31) / 32, 2), 256, 0, stream>>>(pooled, W3, b3, z, G, 256);
    colstats_kernel<<<64, 256, 0, stream>>>(z, G, 256, 8, stC);
    bnfin_kernel<<<1, 256, 0, stream>>>(stC, g3, be3, ssC, G, 256);
    head_kernel<<<G, 256, 0, stream>>>(z, ssC, W4, b4, out, G);
}